// Round 10
// baseline (263.784 us; speedup 1.0000x reference)
//
#include <hip/hip_runtime.h>
#include <math.h>

#define N0 16
#define N1 200
#define N2 200
#define NPIX (N1 * N2)            // 40000
#define NVOX (N0 * NPIX)          // 640000
#define NUM_RAD 223
#define NUM_PHI 190
#define NUM_T 351
#define NSINO (N0 * NUM_PHI * NUM_RAD)  // 677920
// 16-slice interleaved padded layout: 208x208 px (+4 border each side), 2 slack rows
// P16[row][col][s], s = 0..15  -> one 64B cache line per (row,col) position.
#define PITCH16 3328              // 208 cols * 16 slices (floats per row)
#define S16 (3328 * 210)          // 698880 floats per slab
#define BASEOFF16 (4 * 3328 + 4 * 16)   // (+4 rows, +4 cols) origin shift, floats
#define BP_CHUNK 38
#define BP_NCH 5                  // 190 = 5 * 38

// ---------------- constants: replicate numpy linspace / cos / gaussian ----------------
__global__ void init_consts(float* __restrict__ cosb, float* __restrict__ sinb,
                            float* __restrict__ rvb, float* __restrict__ gwb) {
    int t = threadIdx.x;
    const double PI = 3.14159265358979311599796346854418516159;
    if (t < NUM_PHI) {
        double step = PI / 190.0;             // np.linspace(0, pi, 190, endpoint=False)
        float phif = (float)((double)t * step);
        cosb[t] = (float)cos((double)phif);   // np.cos on float32 input
        sinb[t] = (float)sin((double)phif);
    }
    if (t < NUM_RAD) {
        double step = 400.0 / 222.0;          // np.linspace(-200, 200, 223)
        float rv = (float)(-200.0 + (double)t * step);
        if (t == NUM_RAD - 1) rv = 200.0f;    // linspace endpoint fixup
        rvb[t] = rv;
    }
    if (t == 0) {
        double sig = 4.5 / (2.35 * 2.0);
        double g[9], ssum = 0.0;
        for (int k = 0; k < 9; ++k) { double d = (double)(k - 4) / sig; g[k] = exp(-0.5 * d * d); ssum += g[k]; }
        for (int k = 0; k < 9; ++k) gwb[k] = (float)(g[k] / ssum);
    }
}

// ---------------- FUSED forward gaussian, axis0+axis1 in one pass ----------------
// out[i0][i1][i2] = sum_k1 g[k1] * ( sum_k0 g[k0] * x[refl(i0+k0-4)][refl(i1+k1-4)][i2] )
// Inner sum reproduces smooth_fwd(axis0)'s FMA order exactly; outer sum
// reproduces the axis1 pass -> BIT-IDENTICAL to the former two kernels.
// 81 loads/thread, all L2/L3-resident (x = 2.56 MB); saves one launch and a
// 5.1 MB intermediate roundtrip.
__global__ void smooth_fwd01(const float* __restrict__ x, float* __restrict__ out,
                             const float* __restrict__ gwb) {
    int e = blockIdx.x * 256 + threadIdx.x;
    if (e >= NVOX) return;
    int i0 = e / NPIX;
    int rem = e - i0 * NPIX;
    int i1 = rem / N2;
    int i2 = rem - i1 * N2;
    int off0[9];
#pragma unroll
    for (int k = 0; k < 9; ++k) {
        int q = i0 + k - 4;
        q = (q < 0) ? (-1 - q) : ((q >= N0) ? (2 * N0 - 1 - q) : q);
        off0[k] = q * NPIX;
    }
    float outv = 0.f;
#pragma unroll
    for (int k1 = 0; k1 < 9; ++k1) {
        int q1 = i1 + k1 - 4;
        q1 = (q1 < 0) ? (-1 - q1) : ((q1 >= N1) ? (2 * N1 - 1 - q1) : q1);
        int base = q1 * N2 + i2;
        float sv = 0.f;
#pragma unroll
        for (int k0 = 0; k0 < 9; ++k0)
            sv = __fadd_rn(sv, __fmul_rn(gwb[k0], x[off0[k0] + base]));
        outv = __fadd_rn(outv, __fmul_rn(gwb[k1], sv));
    }
    out[e] = outv;
}

// axis-2 pass writing 16-slice interleaved padded layouts:
//   P16[i1+4][i2+4][s] and PT16[i2+4][i1+4][s], pitch 3328 floats.
// Borders are NEVER initialized: only read with weights forced to exactly 0.
__global__ void smooth_fwd2_16(const float* __restrict__ in, float* __restrict__ P16,
                               float* __restrict__ PT16, const float* __restrict__ gwb) {
    int t = blockIdx.x * 256 + threadIdx.x;
    if (t >= 2 * NPIX) return;
    int oct = t & 1;                 // slices oct*8 .. oct*8+7
    int pix = t >> 1;
    int i1 = pix / N2;
    int i2 = pix - i1 * N2;
    int rowbase = i1 * N2;
    float v[8];
#pragma unroll
    for (int jj = 0; jj < 8; ++jj) {
        int i0 = oct * 8 + jj;
        const float* tin = in + i0 * NPIX + rowbase;
        float sum = 0.f;
#pragma unroll
        for (int k = 0; k < 9; ++k) {
            int q = i2 + k - 4;
            q = (q < 0) ? (-1 - q) : ((q >= N2) ? (2 * N2 - 1 - q) : q);
            sum = __fadd_rn(sum, __fmul_rn(gwb[k], tin[q]));
        }
        v[jj] = sum;
    }
    int po  = BASEOFF16 + i1 * PITCH16 + i2 * 16 + oct * 8;
    int pto = BASEOFF16 + i2 * PITCH16 + i1 * 16 + oct * 8;
    *(float4*)(P16 + po)      = make_float4(v[0], v[1], v[2], v[3]);
    *(float4*)(P16 + po + 4)  = make_float4(v[4], v[5], v[6], v[7]);
    *(float4*)(PT16 + pto)     = make_float4(v[0], v[1], v[2], v[3]);
    *(float4*)(PT16 + pto + 4) = make_float4(v[4], v[5], v[6], v[7]);
}

// ---------------- separable gaussian, adjoint (pad-transpose fold) ----------------
__device__ __forceinline__ float adj_u(const float* __restrict__ in, const float* __restrict__ gwb,
                                       int base, int stride, int n, int j) {
    float r = 0.f;
#pragma unroll
    for (int k = 0; k < 9; ++k) {
        int i = j - k;
        if (i >= 0 && i < n) r = __fadd_rn(r, __fmul_rn(gwb[k], in[base + i * stride]));
    }
    return r;
}

__global__ void smooth_adj(const float* __restrict__ in, float* __restrict__ out,
                           const float* __restrict__ gwb, int n, int stride) {
    int e = blockIdx.x * 256 + threadIdx.x;
    if (e >= NVOX) return;
    int a = (e / stride) % n;
    int base = e - a * stride;
    float v = adj_u(in, gwb, base, stride, n, a + 4);
    if (a < 4)      v = __fadd_rn(v, adj_u(in, gwb, base, stride, n, 3 - a));
    if (a >= n - 4) v = __fadd_rn(v, adj_u(in, gwb, base, stride, n, 2 * n + 3 - a));
    out[e] = v;
}

// axis-2 adjoint pass with the 5-partial fold FUSED at each tap.
__device__ __forceinline__ float sum5_at(const float* __restrict__ a, const float* __restrict__ b,
                                         const float* __restrict__ c, const float* __restrict__ d,
                                         const float* __restrict__ e5, int i) {
    return __fadd_rn(__fadd_rn(__fadd_rn(a[i], b[i]), __fadd_rn(c[i], d[i])), e5[i]);
}

__device__ __forceinline__ float adj_u5(const float* __restrict__ a, const float* __restrict__ b,
                                        const float* __restrict__ c, const float* __restrict__ d,
                                        const float* __restrict__ e5, const float* __restrict__ gwb,
                                        int base, int n, int j) {
    float r = 0.f;
#pragma unroll
    for (int k = 0; k < 9; ++k) {
        int i = j - k;
        if (i >= 0 && i < n) r = __fadd_rn(r, __fmul_rn(gwb[k], sum5_at(a, b, c, d, e5, base + i)));
    }
    return r;
}

__global__ void smooth_adj2_sum5(const float* __restrict__ a, const float* __restrict__ b,
                                 const float* __restrict__ c, const float* __restrict__ d,
                                 const float* __restrict__ e5, const float* __restrict__ gwb,
                                 float* __restrict__ out) {
    int e = blockIdx.x * 256 + threadIdx.x;
    if (e >= NVOX) return;
    int i2 = e % N2;            // axis2: stride 1, n = N2
    int base = e - i2;
    float v = adj_u5(a, b, c, d, e5, gwb, base, N2, i2 + 4);
    if (i2 < 4)       v = __fadd_rn(v, adj_u5(a, b, c, d, e5, gwb, base, N2, 3 - i2));
    if (i2 >= N2 - 4) v = __fadd_rn(v, adj_u5(a, b, c, d, e5, gwb, base, N2, 2 * N2 + 3 - i2));
    out[e] = v;
}

// final axis-0 adjoint pass fused with  out = x * v / sens
__global__ void smooth_adj0_final(const float* __restrict__ in, const float* __restrict__ x,
                                  const float* __restrict__ sens, const float* __restrict__ gwb,
                                  float* __restrict__ out) {
    int e = blockIdx.x * 256 + threadIdx.x;
    if (e >= NVOX) return;
    int a = e / NPIX;
    int base = e - a * NPIX;
    float v = adj_u(in, gwb, base, NPIX, N0, a + 4);
    if (a < 4)  v = __fadd_rn(v, adj_u(in, gwb, base, NPIX, N0, 3 - a));
    if (a >= 12) v = __fadd_rn(v, adj_u(in, gwb, base, NPIX, N0, 35 - a));
    out[e] = __fdiv_rn(__fmul_rn(x[e], v), sens[e]);
}

// lean geometry: ix = fma(tv, c/2, Ah), weights pre-masked to exactly 0 when
// invalid (so poison borders contribute exactly 0).
template<bool USET>
__device__ __forceinline__ void geom2(float tv, float ch, float sh, float Ah, float Bh,
                                      float& w00, float& w10, float& w01, float& w11,
                                      int& o) {
    float ix = fmaf(tv, ch, Ah);
    float iy = fmaf(tv, sh, Bh);
    bool valid = (ix >= 0.f) & (ix <= 199.f) & (iy >= 0.f) & (iy <= 199.f);
    float fx = floorf(ix), fy = floorf(iy);
    int ii = (int)fx, jj = (int)fy;       // may be negative: pad covers [-4,203]
    float fi = ix - fx, fj = iy - fy;
    int rowi = USET ? jj : ii;
    int coli = USET ? ii : jj;
    o = rowi * PITCH16 + coli * 16;
    float gi = 1.f - fi, gj = 1.f - fj;
    w00 = valid ? gi * gj : 0.f;
    w10 = valid ? fi * gj : 0.f;
    w01 = valid ? gi * fj : 0.f;
    w11 = valid ? fi * fj : 0.f;
}

#define CONSUME4(W00, W10, W01, W11, V00, V10, V01, V11)                         \
    sums[0] = fmaf(W00, V00.x, sums[0]); sums[0] = fmaf(W10, V10.x, sums[0]);    \
    sums[0] = fmaf(W01, V01.x, sums[0]); sums[0] = fmaf(W11, V11.x, sums[0]);    \
    sums[1] = fmaf(W00, V00.y, sums[1]); sums[1] = fmaf(W10, V10.y, sums[1]);    \
    sums[1] = fmaf(W01, V01.y, sums[1]); sums[1] = fmaf(W11, V11.y, sums[1]);    \
    sums[2] = fmaf(W00, V00.z, sums[2]); sums[2] = fmaf(W10, V10.z, sums[2]);    \
    sums[2] = fmaf(W01, V01.z, sums[2]); sums[2] = fmaf(W11, V11.z, sums[2]);    \
    sums[3] = fmaf(W00, V00.w, sums[3]); sums[3] = fmaf(W10, V10.w, sums[3]);    \
    sums[3] = fmaf(W01, V01.w, sums[3]); sums[3] = fmaf(W11, V11.w, sums[3]);

#define LOADB(DST00, DST10, DST01, DST11, OFF)                                   \
    DST00 = *(const float4*)(basep + (OFF));                                     \
    DST10 = *(const float4*)(basep + (OFF) + O10);                               \
    DST01 = *(const float4*)(basep + (OFF) + O01);                               \
    DST11 = *(const float4*)(basep + (OFF) + O10 + O01);

// k-loop, 3-DEEP pipeline via UNROLL-BY-3 with FIXED A/B/C register roles.
// Round-8 proved the fixed-role recipe (1->2 deep: 102->95us, no spill);
// per-iter VALU issue (~90cyc) still < L1/L2 latency (~150-200cyc), so a
// third in-flight batch covers the residual stall. VGPR ~80, NO cap
// (round-7 lesson). Consumption strictly ascending k, identical FMA order
// -> bit-identical. Tail handles rem = 2/3/4.
template<bool USET>
__device__ __forceinline__ void ray_loop(const float* __restrict__ basep,
                                         int kbeg, int kend, float ch, float sh,
                                         float Ah, float Bh, float sums[4]) {
    constexpr int O10 = USET ? 16 : PITCH16;   // ii+1 step (floats)
    constexpr int O01 = USET ? PITCH16 : 16;   // jj+1 step (floats)
    float tv = (float)(2 * kbeg - 350);
    float aw00, aw10, aw01, aw11; int ao;
    geom2<USET>(tv, ch, sh, Ah, Bh, aw00, aw10, aw01, aw11, ao);
    float4 A00, A10, A01, A11;
    LOADB(A00, A10, A01, A11, ao);
    if (kbeg == kend) {
        CONSUME4(aw00, aw10, aw01, aw11, A00, A10, A01, A11);
        return;
    }
    float bw00, bw10, bw01, bw11; int bo;
    tv += 2.0f;
    geom2<USET>(tv, ch, sh, Ah, Bh, bw00, bw10, bw01, bw11, bo);
    float4 B00, B10, B01, B11;
    LOADB(B00, B10, B01, B11, bo);
    if (kbeg + 1 == kend) {
        CONSUME4(aw00, aw10, aw01, aw11, A00, A10, A01, A11);
        CONSUME4(bw00, bw10, bw01, bw11, B00, B10, B01, B11);
        return;
    }
    float cw00, cw10, cw01, cw11; int co;
    tv += 2.0f;
    geom2<USET>(tv, ch, sh, Ah, Bh, cw00, cw10, cw01, cw11, co);
    float4 C00, C10, C01, C11;
    LOADB(C00, C10, C01, C11, co);
    int k = kbeg;               // invariant: A=k, B=k+1, C=k+2, tv = t(k+2)
#pragma unroll 1
    while (k + 5 <= kend) {
        CONSUME4(aw00, aw10, aw01, aw11, A00, A10, A01, A11);   // consume k
        tv += 2.0f;
        geom2<USET>(tv, ch, sh, Ah, Bh, aw00, aw10, aw01, aw11, ao);
        LOADB(A00, A10, A01, A11, ao);                          // stage k+3
        CONSUME4(bw00, bw10, bw01, bw11, B00, B10, B01, B11);   // consume k+1
        tv += 2.0f;
        geom2<USET>(tv, ch, sh, Ah, Bh, bw00, bw10, bw01, bw11, bo);
        LOADB(B00, B10, B01, B11, bo);                          // stage k+4
        CONSUME4(cw00, cw10, cw01, cw11, C00, C10, C01, C11);   // consume k+2
        tv += 2.0f;
        geom2<USET>(tv, ch, sh, Ah, Bh, cw00, cw10, cw01, cw11, co);
        LOADB(C00, C10, C01, C11, co);                          // stage k+5
        k += 3;
    }
    int rem = kend - k;         // 2, 3, or 4
    CONSUME4(aw00, aw10, aw01, aw11, A00, A10, A01, A11);       // k
    if (rem >= 3) {
        tv += 2.0f;
        geom2<USET>(tv, ch, sh, Ah, Bh, aw00, aw10, aw01, aw11, ao);
        LOADB(A00, A10, A01, A11, ao);                          // stage k+3
    }
    CONSUME4(bw00, bw10, bw01, bw11, B00, B10, B01, B11);       // k+1
    if (rem == 4) {
        tv += 2.0f;
        geom2<USET>(tv, ch, sh, Ah, Bh, bw00, bw10, bw01, bw11, bo);
        LOADB(B00, B10, B01, B11, bo);                          // stage k+4
    }
    CONSUME4(cw00, cw10, cw01, cw11, C00, C10, C01, C11);       // k+2
    if (rem >= 3) { CONSUME4(aw00, aw10, aw01, aw11, A00, A10, A01, A11); }  // k+3
    if (rem == 4) { CONSUME4(bw00, bw10, bw01, bw11, B00, B10, B01, B11); }  // k+4
}

// ---------------- forward projection + ratio, fused ----------------
// ROUND-3 LOCALITY OPTIMUM (FETCH 14.7 MB): 760 blocks = 190 phi x 4
// consecutive-r chunks; XCD swizzle gives each XCD 95 consecutive sw ->
// image working set stays XCD-L2-resident. launch_bounds(512,2) (no VGPR
// cap -> no spill). 3-deep fixed-role pipeline; VGPR ~80 -> 6 waves/SIMD
// -> 3 blocks/CU -> 768 slots >= 760 (single dispatch round).
// block (256,2): x = rr*4 + slice-chunk, y = t-half. zt bit-identical.
__global__ __launch_bounds__(512, 2)
void project_ratio(const float* __restrict__ P16, const float* __restrict__ PT16,
                   const float* __restrict__ data,
                   const float* __restrict__ contam, const float* __restrict__ mult,
                   const float* __restrict__ cosb, const float* __restrict__ sinb,
                   const float* __restrict__ rvb, float* __restrict__ zt) {
    int b = blockIdx.x;
    int sw = (b & 7) * 95 + (b >> 3);   // bijective XCD swizzle (760 = 8*95)
    int rc  = sw / NUM_PHI;             // radial chunk 0..3
    int phi = sw - rc * NUM_PHI;
    int tx = threadIdx.x;
    int chunk = tx & 3;                 // slice quad: slices chunk*4 .. chunk*4+3
    int rr = tx >> 2;                   // r within chunk, 0..63
    int r = rc * 64 + rr;               // consecutive radial decomposition
    int half = threadIdx.y;
    bool active = (r < NUM_RAD);

    __shared__ float part[4][256];

    float sums[4] = {0.f, 0.f, 0.f, 0.f};
    float c = cosb[phi], sp = sinb[phi];
    float ch = c * 0.5f, sh = sp * 0.5f;   // exact halves

    bool useT = fabsf(sp) > fabsf(c);
    const float* basep = (useT ? PT16 : P16) + BASEOFF16 + chunk * 4;

    if (active) {
        float rv = rvb[r];
        float A = __fmul_rn(rv, -sp);   // RV * (-s)  (window calc)
        float B = __fmul_rn(rv, c);     // RV * c
        float Ah = fmaf(rv, -sh, 99.5f);  // (A + 199)/2 up to 1-2 ulp
        float Bh = fmaf(rv, ch, 99.5f);

        // conservative valid-t window
        float tlo = -350.f, thi = 350.f;
        bool empty = false;
        if (fabsf(c) > 1e-6f) {
            float a0 = (-199.f - A) / c, b0 = (199.f - A) / c;
            tlo = fmaxf(tlo, fminf(a0, b0)); thi = fminf(thi, fmaxf(a0, b0));
        } else if (fabsf(A) > 199.5f) empty = true;
        if (fabsf(sp) > 1e-6f) {
            float a0 = (-199.f - B) / sp, b0 = (199.f - B) / sp;
            tlo = fmaxf(tlo, fminf(a0, b0)); thi = fminf(thi, fmaxf(a0, b0));
        } else if (fabsf(B) > 199.5f) empty = true;

        int klo = max(0, (int)floorf((tlo + 350.f) * 0.5f) - 1);
        int khi = min(NUM_T - 1, (int)ceilf((thi + 350.f) * 0.5f) + 1);

        if (!empty && klo <= khi) {
            int kmid = (klo + khi + 1) >> 1;
            int kbeg = half ? kmid : klo;
            int kend = half ? khi : (kmid - 1);
            if (kbeg <= kend) {
                if (useT) ray_loop<true>(basep, kbeg, kend, ch, sh, Ah, Bh, sums);
                else      ray_loop<false>(basep, kbeg, kend, ch, sh, Ah, Bh, sums);
            }
        }
    }

    if (half == 1) {
#pragma unroll
        for (int s = 0; s < 4; ++s) part[s][tx] = sums[s];
    }
    __syncthreads();
    if (half == 0 && active) {
#pragma unroll
        for (int s = 0; s < 4; ++s) {
            float proj = __fmul_rn(__fadd_rn(sums[s], part[s][tx]), 2.0f);  // * STEP
            int sl = chunk * 4 + s;
            int idx = (sl * NUM_PHI + phi) * NUM_RAD + r;
            float ex = __fadd_rn(__fmul_rn(mult[idx], proj), contam[idx]);
            float zval = __fmul_rn(mult[idx], __fdiv_rn(data[idx], ex));
            zt[(phi * NUM_RAD + r) * N0 + sl] = zval;
        }
    }
}

// ---------------- adjoint projection: 4-lane cooperative gather, no atomics ----------------
// ROUND-8 FORM RESTORED (round-9 pipeline was neutral: BP is already near
// its zt line-touch floor ~50us; latency-hiding had nothing to reclaim).
// thread = (pixel, slice-quad); own-dj weight; __shfl all-gather; 5 private
// partial volumes with plain stores; smooth_adj2_sum5 folds them inline.
__global__ __launch_bounds__(256, 6)
void backproject(const float* __restrict__ zt, const float* __restrict__ cosb,
                 const float* __restrict__ sinb, const float* __restrict__ rvb,
                 float* __restrict__ q0, float* __restrict__ q1, float* __restrict__ q2,
                 float* __restrict__ q3, float* __restrict__ q4) {
    int tx = threadIdx.x;
    int q = tx & 3;                       // slice-quad: slices q*4 .. q*4+3
    int pix = blockIdx.x * 64 + (tx >> 2);
    int pc = blockIdx.y;
    int i1 = pix / N2;
    int i2 = pix - i1 * N2;
    float X1 = 2.f * (float)i1 - 199.f;   // ORG1 + i1*VOX (exact)
    float X2 = 2.f * (float)i2 - 199.f;
    float i1f = (float)i1, i2f = (float)i2;
    int lb = tx & 60;                     // wave-lane base of the 4-group
    float acc[4] = {0.f, 0.f, 0.f, 0.f};

    int p_end = pc * BP_CHUNK + BP_CHUNK;
    for (int p = pc * BP_CHUNK; p < p_end; ++p) {
        float c = cosb[p], sp = sinb[p];
        float ch = c * 0.5f, sh = sp * 0.5f;
        float tp = c * X1 + sp * X2;
        float rp = c * X2 - sp * X1;
        int j0 = (int)floorf((rp + 200.f) * 0.555f);   // conservative bin
        int jb = min(max(j0 - 1, 0), NUM_RAD - 4);
        float tc = (tp + 350.f) * 0.5f;
        int kc = (int)floorf(tc + 0.5f);

        // cooperative row loads: 4 lanes cover each 64B zt row
        const float4* zb = (const float4*)(zt + (p * NUM_RAD + jb) * N0);
        float4 Z0 = zb[q];
        float4 Z1 = zb[4 + q];
        float4 Z2 = zb[8 + q];
        float4 Z3 = zb[12 + q];

        // own-dj (dj = q) bilinear weight
        float tvc = (float)(2 * kc - 350);
        float Qx[3], Qy[3];
#pragma unroll
        for (int dk = 0; dk < 3; ++dk) {
            float tv = tvc + (float)(2 * (dk - 1));
            Qx[dk] = fmaf(tv, ch, 99.5f);
            Qy[dk] = fmaf(tv, sh, 99.5f);
        }
        float rvj = rvb[jb + q];
        float Px = rvj * (-sh);
        float Py = rvj * ch;
        float w = 0.f;
#pragma unroll
        for (int dk = 0; dk < 3; ++dk) {
            float ix = Px + Qx[dk];
            float iy = Py + Qy[dk];
            bool valid = (ix >= 0.f) & (ix <= 199.f) & (iy >= 0.f) & (iy <= 199.f);
            float wx = fmaxf(0.f, 1.f - fabsf(ix - i1f));
            float wy = fmaxf(0.f, 1.f - fabsf(iy - i2f));
            float wxm = valid ? wx : 0.f;
            w = fmaf(wxm, wy, w);
        }

        // all-gather the 4 dj-weights within the pixel-group (dj ascending)
        float w0 = __shfl(w, lb + 0);
        float w1 = __shfl(w, lb + 1);
        float w2 = __shfl(w, lb + 2);
        float w3 = __shfl(w, lb + 3);

        acc[0] = fmaf(w0, Z0.x, acc[0]); acc[1] = fmaf(w0, Z0.y, acc[1]);
        acc[2] = fmaf(w0, Z0.z, acc[2]); acc[3] = fmaf(w0, Z0.w, acc[3]);
        acc[0] = fmaf(w1, Z1.x, acc[0]); acc[1] = fmaf(w1, Z1.y, acc[1]);
        acc[2] = fmaf(w1, Z1.z, acc[2]); acc[3] = fmaf(w1, Z1.w, acc[3]);
        acc[0] = fmaf(w2, Z2.x, acc[0]); acc[1] = fmaf(w2, Z2.y, acc[1]);
        acc[2] = fmaf(w2, Z2.z, acc[2]); acc[3] = fmaf(w2, Z2.w, acc[3]);
        acc[0] = fmaf(w3, Z3.x, acc[0]); acc[1] = fmaf(w3, Z3.y, acc[1]);
        acc[2] = fmaf(w3, Z3.z, acc[2]); acc[3] = fmaf(w3, Z3.w, acc[3]);
    }

    float* pp = (pc == 0) ? q0 : (pc == 1) ? q1 : (pc == 2) ? q2 : (pc == 3) ? q3 : q4;
#pragma unroll
    for (int i = 0; i < 4; ++i)
        pp[(q * 4 + i) * NPIX + pix] = acc[i] * 2.0f;   // * STEP, plain store
}

extern "C" void kernel_launch(void* const* d_in, const int* in_sizes, int n_in,
                              void* d_out, int out_size, void* d_ws, size_t ws_size,
                              hipStream_t stream) {
    const float* x      = (const float*)d_in[0];
    const float* data   = (const float*)d_in[1];
    const float* contam = (const float*)d_in[2];
    const float* mult   = (const float*)d_in[3];
    const float* sens   = (const float*)d_in[4];
    float* out = (float*)d_out;

    float* W    = (float*)d_ws;
    float* s    = W;                        // 640000
    float* tmp  = W + NVOX;                 // 640000
    float* bp2  = W + 2 * NVOX;             // 640000
    float* zt   = W + 3 * NVOX;             // 677920
    float* P16  = W + 3 * NVOX + NSINO;     // 698880
    float* PT16 = P16 + S16;                // 698880
    float* cosb = PT16 + S16;
    float* sinb = cosb + NUM_PHI;
    float* rvb  = sinb + NUM_PHI;
    float* gwb  = rvb + NUM_RAD;

    hipLaunchKernelGGL(init_consts, dim3(1), dim3(256), 0, stream, cosb, sinb, rvb, gwb);

    // gauss3 forward: x -> tmp (FUSED axis0+axis1), tmp -> {P16, PT16} (axis2, 16-interleave)
    int nb = (NVOX + 255) / 256;
    hipLaunchKernelGGL(smooth_fwd01, dim3(nb), dim3(256), 0, stream, x, tmp, gwb);
    int nb2 = (2 * NPIX + 255) / 256;
    hipLaunchKernelGGL(smooth_fwd2_16, dim3(nb2), dim3(256), 0, stream, tmp, P16, PT16, gwb);

    // forward project + ratio (writes zt): 760 blocks, round-3 XCD swizzle
    hipLaunchKernelGGL(project_ratio, dim3(NUM_PHI * 4), dim3(256, 2), 0, stream,
                       P16, PT16, data, contam, mult, cosb, sinb, rvb, zt);

    // backproject: 5 private partial volumes in dead buffers (s, tmp, bp2, P16, PT16)
    hipLaunchKernelGGL(backproject, dim3(NPIX / 64, BP_NCH), dim3(256), 0, stream,
                       zt, cosb, sinb, rvb, s, tmp, bp2, P16, PT16);

    // gauss3 adjoint with fused 5-partial fold:
    //   {q0..q4} -> zt (axis2^T + sum5), zt -> s (axis1^T), s -> out (axis0^T fused final)
    hipLaunchKernelGGL(smooth_adj2_sum5, dim3(nb), dim3(256), 0, stream,
                       s, tmp, bp2, P16, PT16, gwb, zt);
    hipLaunchKernelGGL(smooth_adj, dim3(nb), dim3(256), 0, stream, zt, s, gwb, N1, N2);
    hipLaunchKernelGGL(smooth_adj0_final, dim3(nb), dim3(256), 0, stream, s, x, sens, gwb, out);
}

// Round 11
// 259.812 us; speedup vs baseline: 1.0153x; 1.0153x over previous
//
#include <hip/hip_runtime.h>
#include <math.h>

#define N0 16
#define N1 200
#define N2 200
#define NPIX (N1 * N2)            // 40000
#define NVOX (N0 * NPIX)          // 640000
#define NUM_RAD 223
#define NUM_PHI 190
#define NUM_T 351
#define NSINO (N0 * NUM_PHI * NUM_RAD)  // 677920
// 16-slice interleaved padded layout: 208x208 px (+4 border each side), 2 slack rows
// P16[row][col][s], s = 0..15  -> one 64B cache line per (row,col) position.
#define PITCH16 3328              // 208 cols * 16 slices (floats per row)
#define S16 (3328 * 210)          // 698880 floats per slab
#define BASEOFF16 (4 * 3328 + 4 * 16)   // (+4 rows, +4 cols) origin shift, floats
#define BP_CHUNK 38
#define BP_NCH 5                  // 190 = 5 * 38

// ---------------- constants: replicate numpy linspace / cos / gaussian ----------------
__global__ void init_consts(float* __restrict__ cosb, float* __restrict__ sinb,
                            float* __restrict__ rvb, float* __restrict__ gwb) {
    int t = threadIdx.x;
    const double PI = 3.14159265358979311599796346854418516159;
    if (t < NUM_PHI) {
        double step = PI / 190.0;             // np.linspace(0, pi, 190, endpoint=False)
        float phif = (float)((double)t * step);
        cosb[t] = (float)cos((double)phif);   // np.cos on float32 input
        sinb[t] = (float)sin((double)phif);
    }
    if (t < NUM_RAD) {
        double step = 400.0 / 222.0;          // np.linspace(-200, 200, 223)
        float rv = (float)(-200.0 + (double)t * step);
        if (t == NUM_RAD - 1) rv = 200.0f;    // linspace endpoint fixup
        rvb[t] = rv;
    }
    if (t == 0) {
        double sig = 4.5 / (2.35 * 2.0);
        double g[9], ssum = 0.0;
        for (int k = 0; k < 9; ++k) { double d = (double)(k - 4) / sig; g[k] = exp(-0.5 * d * d); ssum += g[k]; }
        for (int k = 0; k < 9; ++k) gwb[k] = (float)(g[k] / ssum);
    }
}

// ---------------- separable gaussian, forward (symmetric pad) ----------------
__global__ void smooth_fwd(const float* __restrict__ in, float* __restrict__ out,
                           const float* __restrict__ gwb, int n, int stride) {
    int e = blockIdx.x * 256 + threadIdx.x;
    if (e >= NVOX) return;
    int a = (e / stride) % n;
    int base = e - a * stride;
    float sum = 0.f;
#pragma unroll
    for (int k = 0; k < 9; ++k) {
        int q = a + k - 4;
        q = (q < 0) ? (-1 - q) : ((q >= n) ? (2 * n - 1 - q) : q);
        sum = __fadd_rn(sum, __fmul_rn(gwb[k], in[base + q * stride]));
    }
    out[e] = sum;
}

// axis-2 pass writing 16-slice interleaved padded layouts:
//   P16[i1+4][i2+4][s] and PT16[i2+4][i1+4][s], pitch 3328 floats.
// Borders are NEVER initialized: only read with weights forced to exactly 0.
__global__ void smooth_fwd2_16(const float* __restrict__ in, float* __restrict__ P16,
                               float* __restrict__ PT16, const float* __restrict__ gwb) {
    int t = blockIdx.x * 256 + threadIdx.x;
    if (t >= 2 * NPIX) return;
    int oct = t & 1;                 // slices oct*8 .. oct*8+7
    int pix = t >> 1;
    int i1 = pix / N2;
    int i2 = pix - i1 * N2;
    int rowbase = i1 * N2;
    float v[8];
#pragma unroll
    for (int jj = 0; jj < 8; ++jj) {
        int i0 = oct * 8 + jj;
        const float* tin = in + i0 * NPIX + rowbase;
        float sum = 0.f;
#pragma unroll
        for (int k = 0; k < 9; ++k) {
            int q = i2 + k - 4;
            q = (q < 0) ? (-1 - q) : ((q >= N2) ? (2 * N2 - 1 - q) : q);
            sum = __fadd_rn(sum, __fmul_rn(gwb[k], tin[q]));
        }
        v[jj] = sum;
    }
    int po  = BASEOFF16 + i1 * PITCH16 + i2 * 16 + oct * 8;
    int pto = BASEOFF16 + i2 * PITCH16 + i1 * 16 + oct * 8;
    *(float4*)(P16 + po)      = make_float4(v[0], v[1], v[2], v[3]);
    *(float4*)(P16 + po + 4)  = make_float4(v[4], v[5], v[6], v[7]);
    *(float4*)(PT16 + pto)     = make_float4(v[0], v[1], v[2], v[3]);
    *(float4*)(PT16 + pto + 4) = make_float4(v[4], v[5], v[6], v[7]);
}

// ---------------- separable gaussian, adjoint (pad-transpose fold) ----------------
__device__ __forceinline__ float adj_u(const float* __restrict__ in, const float* __restrict__ gwb,
                                       int base, int stride, int n, int j) {
    float r = 0.f;
#pragma unroll
    for (int k = 0; k < 9; ++k) {
        int i = j - k;
        if (i >= 0 && i < n) r = __fadd_rn(r, __fmul_rn(gwb[k], in[base + i * stride]));
    }
    return r;
}

__global__ void smooth_adj(const float* __restrict__ in, float* __restrict__ out,
                           const float* __restrict__ gwb, int n, int stride) {
    int e = blockIdx.x * 256 + threadIdx.x;
    if (e >= NVOX) return;
    int a = (e / stride) % n;
    int base = e - a * stride;
    float v = adj_u(in, gwb, base, stride, n, a + 4);
    if (a < 4)      v = __fadd_rn(v, adj_u(in, gwb, base, stride, n, 3 - a));
    if (a >= n - 4) v = __fadd_rn(v, adj_u(in, gwb, base, stride, n, 2 * n + 3 - a));
    out[e] = v;
}

// axis-2 adjoint pass with the 5-partial fold FUSED at each tap.
// sum tree per tap is identical to the old sum5 kernel (((a+b)+(c+d))+e),
// then the same adj_u accumulation order -> bit-identical result.
__device__ __forceinline__ float sum5_at(const float* __restrict__ a, const float* __restrict__ b,
                                         const float* __restrict__ c, const float* __restrict__ d,
                                         const float* __restrict__ e5, int i) {
    return __fadd_rn(__fadd_rn(__fadd_rn(a[i], b[i]), __fadd_rn(c[i], d[i])), e5[i]);
}

__device__ __forceinline__ float adj_u5(const float* __restrict__ a, const float* __restrict__ b,
                                        const float* __restrict__ c, const float* __restrict__ d,
                                        const float* __restrict__ e5, const float* __restrict__ gwb,
                                        int base, int n, int j) {
    float r = 0.f;
#pragma unroll
    for (int k = 0; k < 9; ++k) {
        int i = j - k;
        if (i >= 0 && i < n) r = __fadd_rn(r, __fmul_rn(gwb[k], sum5_at(a, b, c, d, e5, base + i)));
    }
    return r;
}

__global__ void smooth_adj2_sum5(const float* __restrict__ a, const float* __restrict__ b,
                                 const float* __restrict__ c, const float* __restrict__ d,
                                 const float* __restrict__ e5, const float* __restrict__ gwb,
                                 float* __restrict__ out) {
    int e = blockIdx.x * 256 + threadIdx.x;
    if (e >= NVOX) return;
    int i2 = e % N2;            // axis2: stride 1, n = N2
    int base = e - i2;
    float v = adj_u5(a, b, c, d, e5, gwb, base, N2, i2 + 4);
    if (i2 < 4)       v = __fadd_rn(v, adj_u5(a, b, c, d, e5, gwb, base, N2, 3 - i2));
    if (i2 >= N2 - 4) v = __fadd_rn(v, adj_u5(a, b, c, d, e5, gwb, base, N2, 2 * N2 + 3 - i2));
    out[e] = v;
}

// final axis-0 adjoint pass fused with  out = x * v / sens
__global__ void smooth_adj0_final(const float* __restrict__ in, const float* __restrict__ x,
                                  const float* __restrict__ sens, const float* __restrict__ gwb,
                                  float* __restrict__ out) {
    int e = blockIdx.x * 256 + threadIdx.x;
    if (e >= NVOX) return;
    int a = e / NPIX;
    int base = e - a * NPIX;
    float v = adj_u(in, gwb, base, NPIX, N0, a + 4);
    if (a < 4)  v = __fadd_rn(v, adj_u(in, gwb, base, NPIX, N0, 3 - a));
    if (a >= 12) v = __fadd_rn(v, adj_u(in, gwb, base, NPIX, N0, 35 - a));
    out[e] = __fdiv_rn(__fmul_rn(x[e], v), sens[e]);
}

// lean geometry: ix = fma(tv, c/2, Ah), weights pre-masked to exactly 0 when
// invalid (so poison borders contribute exactly 0).
template<bool USET>
__device__ __forceinline__ void geom2(float tv, float ch, float sh, float Ah, float Bh,
                                      float& w00, float& w10, float& w01, float& w11,
                                      int& o) {
    float ix = fmaf(tv, ch, Ah);
    float iy = fmaf(tv, sh, Bh);
    bool valid = (ix >= 0.f) & (ix <= 199.f) & (iy >= 0.f) & (iy <= 199.f);
    float fx = floorf(ix), fy = floorf(iy);
    int ii = (int)fx, jj = (int)fy;       // may be negative: pad covers [-4,203]
    float fi = ix - fx, fj = iy - fy;
    int rowi = USET ? jj : ii;
    int coli = USET ? ii : jj;
    o = rowi * PITCH16 + coli * 16;
    float gi = 1.f - fi, gj = 1.f - fj;
    w00 = valid ? gi * gj : 0.f;
    w10 = valid ? fi * gj : 0.f;
    w01 = valid ? gi * fj : 0.f;
    w11 = valid ? fi * fj : 0.f;
}

#define CONSUME4(W00, W10, W01, W11, V00, V10, V01, V11)                         \
    sums[0] = fmaf(W00, V00.x, sums[0]); sums[0] = fmaf(W10, V10.x, sums[0]);    \
    sums[0] = fmaf(W01, V01.x, sums[0]); sums[0] = fmaf(W11, V11.x, sums[0]);    \
    sums[1] = fmaf(W00, V00.y, sums[1]); sums[1] = fmaf(W10, V10.y, sums[1]);    \
    sums[1] = fmaf(W01, V01.y, sums[1]); sums[1] = fmaf(W11, V11.y, sums[1]);    \
    sums[2] = fmaf(W00, V00.z, sums[2]); sums[2] = fmaf(W10, V10.z, sums[2]);    \
    sums[2] = fmaf(W01, V01.z, sums[2]); sums[2] = fmaf(W11, V11.z, sums[2]);    \
    sums[3] = fmaf(W00, V00.w, sums[3]); sums[3] = fmaf(W10, V10.w, sums[3]);    \
    sums[3] = fmaf(W01, V01.w, sums[3]); sums[3] = fmaf(W11, V11.w, sums[3]);

#define LOADB(DST00, DST10, DST01, DST11, OFF)                                   \
    DST00 = *(const float4*)(basep + (OFF));                                     \
    DST10 = *(const float4*)(basep + (OFF) + O10);                               \
    DST01 = *(const float4*)(basep + (OFF) + O01);                               \
    DST11 = *(const float4*)(basep + (OFF) + O10 + O01);

// k-loop, 2-deep pipeline via UNROLL-BY-2 with FIXED A/B register roles.
// Round-8 proven optimum: VGPR 52 sits exactly at the 4-blocks/CU register
// boundary (<=64); round-10's 3-deep (VGPR 76) lost more occupancy than it
// gained in latency cover. Round-7 lesson: no rotating regs, no VGPR cap.
// Two 4-load batches permanently in flight; compiler emits counted vmcnt
// before each consume -> a wave stalls at most once per TWO batches.
// Consumption strictly ascending k, identical FMA order -> bit-identical.
template<bool USET>
__device__ __forceinline__ void ray_loop(const float* __restrict__ basep,
                                         int kbeg, int kend, float ch, float sh,
                                         float Ah, float Bh, float sums[4]) {
    constexpr int O10 = USET ? 16 : PITCH16;   // ii+1 step (floats)
    constexpr int O01 = USET ? PITCH16 : 16;   // jj+1 step (floats)
    float tv = (float)(2 * kbeg - 350);
    float aw00, aw10, aw01, aw11; int ao;
    geom2<USET>(tv, ch, sh, Ah, Bh, aw00, aw10, aw01, aw11, ao);
    float4 A00, A10, A01, A11;
    LOADB(A00, A10, A01, A11, ao);
    if (kbeg == kend) {
        CONSUME4(aw00, aw10, aw01, aw11, A00, A10, A01, A11);
        return;
    }
    float bw00, bw10, bw01, bw11; int bo;
    tv += 2.0f;
    geom2<USET>(tv, ch, sh, Ah, Bh, bw00, bw10, bw01, bw11, bo);
    float4 B00, B10, B01, B11;
    LOADB(B00, B10, B01, B11, bo);
    int k = kbeg;                       // invariant: A holds k, B holds k+1
#pragma unroll 1
    while (k + 3 <= kend) {
        CONSUME4(aw00, aw10, aw01, aw11, A00, A10, A01, A11);   // consume k
        tv += 2.0f;
        geom2<USET>(tv, ch, sh, Ah, Bh, aw00, aw10, aw01, aw11, ao);
        LOADB(A00, A10, A01, A11, ao);                          // prefetch k+2
        CONSUME4(bw00, bw10, bw01, bw11, B00, B10, B01, B11);   // consume k+1
        tv += 2.0f;
        geom2<USET>(tv, ch, sh, Ah, Bh, bw00, bw10, bw01, bw11, bo);
        LOADB(B00, B10, B01, B11, bo);                          // prefetch k+3
        k += 2;
    }
    // tail: kend - k is 1 or 2
    if (kend == k + 1) {
        CONSUME4(aw00, aw10, aw01, aw11, A00, A10, A01, A11);
        CONSUME4(bw00, bw10, bw01, bw11, B00, B10, B01, B11);
    } else {                            // kend == k + 2
        CONSUME4(aw00, aw10, aw01, aw11, A00, A10, A01, A11);
        tv += 2.0f;
        geom2<USET>(tv, ch, sh, Ah, Bh, aw00, aw10, aw01, aw11, ao);
        LOADB(A00, A10, A01, A11, ao);
        CONSUME4(bw00, bw10, bw01, bw11, B00, B10, B01, B11);
        CONSUME4(aw00, aw10, aw01, aw11, A00, A10, A01, A11);
    }
}

// ---------------- forward projection + ratio, fused ----------------
// ROUND-3 LOCALITY OPTIMUM (FETCH 14.7 MB): 760 blocks = 190 phi x 4
// consecutive-r chunks; XCD swizzle gives each XCD 95 consecutive sw ->
// image working set stays XCD-L2-resident. launch_bounds(512,2) (no VGPR
// cap -> no spill; VGPR 52 -> 4 blocks/CU). 2-deep fixed-role pipeline.
// block (256,2): x = rr*4 + slice-chunk, y = t-half. zt bit-identical.
__global__ __launch_bounds__(512, 2)
void project_ratio(const float* __restrict__ P16, const float* __restrict__ PT16,
                   const float* __restrict__ data,
                   const float* __restrict__ contam, const float* __restrict__ mult,
                   const float* __restrict__ cosb, const float* __restrict__ sinb,
                   const float* __restrict__ rvb, float* __restrict__ zt) {
    int b = blockIdx.x;
    int sw = (b & 7) * 95 + (b >> 3);   // bijective XCD swizzle (760 = 8*95)
    int rc  = sw / NUM_PHI;             // radial chunk 0..3
    int phi = sw - rc * NUM_PHI;
    int tx = threadIdx.x;
    int chunk = tx & 3;                 // slice quad: slices chunk*4 .. chunk*4+3
    int rr = tx >> 2;                   // r within chunk, 0..63
    int r = rc * 64 + rr;               // consecutive radial decomposition
    int half = threadIdx.y;
    bool active = (r < NUM_RAD);

    __shared__ float part[4][256];

    float sums[4] = {0.f, 0.f, 0.f, 0.f};
    float c = cosb[phi], sp = sinb[phi];
    float ch = c * 0.5f, sh = sp * 0.5f;   // exact halves

    bool useT = fabsf(sp) > fabsf(c);
    const float* basep = (useT ? PT16 : P16) + BASEOFF16 + chunk * 4;

    if (active) {
        float rv = rvb[r];
        float A = __fmul_rn(rv, -sp);   // RV * (-s)  (window calc)
        float B = __fmul_rn(rv, c);     // RV * c
        float Ah = fmaf(rv, -sh, 99.5f);  // (A + 199)/2 up to 1-2 ulp
        float Bh = fmaf(rv, ch, 99.5f);

        // conservative valid-t window
        float tlo = -350.f, thi = 350.f;
        bool empty = false;
        if (fabsf(c) > 1e-6f) {
            float a0 = (-199.f - A) / c, b0 = (199.f - A) / c;
            tlo = fmaxf(tlo, fminf(a0, b0)); thi = fminf(thi, fmaxf(a0, b0));
        } else if (fabsf(A) > 199.5f) empty = true;
        if (fabsf(sp) > 1e-6f) {
            float a0 = (-199.f - B) / sp, b0 = (199.f - B) / sp;
            tlo = fmaxf(tlo, fminf(a0, b0)); thi = fminf(thi, fmaxf(a0, b0));
        } else if (fabsf(B) > 199.5f) empty = true;

        int klo = max(0, (int)floorf((tlo + 350.f) * 0.5f) - 1);
        int khi = min(NUM_T - 1, (int)ceilf((thi + 350.f) * 0.5f) + 1);

        if (!empty && klo <= khi) {
            int kmid = (klo + khi + 1) >> 1;
            int kbeg = half ? kmid : klo;
            int kend = half ? khi : (kmid - 1);
            if (kbeg <= kend) {
                if (useT) ray_loop<true>(basep, kbeg, kend, ch, sh, Ah, Bh, sums);
                else      ray_loop<false>(basep, kbeg, kend, ch, sh, Ah, Bh, sums);
            }
        }
    }

    if (half == 1) {
#pragma unroll
        for (int s = 0; s < 4; ++s) part[s][tx] = sums[s];
    }
    __syncthreads();
    if (half == 0 && active) {
#pragma unroll
        for (int s = 0; s < 4; ++s) {
            float proj = __fmul_rn(__fadd_rn(sums[s], part[s][tx]), 2.0f);  // * STEP
            int sl = chunk * 4 + s;
            int idx = (sl * NUM_PHI + phi) * NUM_RAD + r;
            float ex = __fadd_rn(__fmul_rn(mult[idx], proj), contam[idx]);
            float zval = __fmul_rn(mult[idx], __fdiv_rn(data[idx], ex));
            zt[(phi * NUM_RAD + r) * N0 + sl] = zval;
        }
    }
}

// ---------------- adjoint projection: 4-lane cooperative gather, no atomics ----------------
// ROUND-8 FORM (round-9 pipeline was neutral: BP is already near its zt
// line-touch floor ~50us; latency-hiding had nothing to reclaim).
// thread = (pixel, slice-quad); own-dj weight; __shfl all-gather; 5 private
// partial volumes with plain stores; smooth_adj2_sum5 folds them inline.
__global__ __launch_bounds__(256, 6)
void backproject(const float* __restrict__ zt, const float* __restrict__ cosb,
                 const float* __restrict__ sinb, const float* __restrict__ rvb,
                 float* __restrict__ q0, float* __restrict__ q1, float* __restrict__ q2,
                 float* __restrict__ q3, float* __restrict__ q4) {
    int tx = threadIdx.x;
    int q = tx & 3;                       // slice-quad: slices q*4 .. q*4+3
    int pix = blockIdx.x * 64 + (tx >> 2);
    int pc = blockIdx.y;
    int i1 = pix / N2;
    int i2 = pix - i1 * N2;
    float X1 = 2.f * (float)i1 - 199.f;   // ORG1 + i1*VOX (exact)
    float X2 = 2.f * (float)i2 - 199.f;
    float i1f = (float)i1, i2f = (float)i2;
    int lb = tx & 60;                     // wave-lane base of the 4-group
    float acc[4] = {0.f, 0.f, 0.f, 0.f};

    int p_end = pc * BP_CHUNK + BP_CHUNK;
    for (int p = pc * BP_CHUNK; p < p_end; ++p) {
        float c = cosb[p], sp = sinb[p];
        float ch = c * 0.5f, sh = sp * 0.5f;
        float tp = c * X1 + sp * X2;
        float rp = c * X2 - sp * X1;
        int j0 = (int)floorf((rp + 200.f) * 0.555f);   // conservative bin
        int jb = min(max(j0 - 1, 0), NUM_RAD - 4);
        float tc = (tp + 350.f) * 0.5f;
        int kc = (int)floorf(tc + 0.5f);

        // cooperative row loads: 4 lanes cover each 64B zt row
        const float4* zb = (const float4*)(zt + (p * NUM_RAD + jb) * N0);
        float4 Z0 = zb[q];
        float4 Z1 = zb[4 + q];
        float4 Z2 = zb[8 + q];
        float4 Z3 = zb[12 + q];

        // own-dj (dj = q) bilinear weight
        float tvc = (float)(2 * kc - 350);
        float Qx[3], Qy[3];
#pragma unroll
        for (int dk = 0; dk < 3; ++dk) {
            float tv = tvc + (float)(2 * (dk - 1));
            Qx[dk] = fmaf(tv, ch, 99.5f);
            Qy[dk] = fmaf(tv, sh, 99.5f);
        }
        float rvj = rvb[jb + q];
        float Px = rvj * (-sh);
        float Py = rvj * ch;
        float w = 0.f;
#pragma unroll
        for (int dk = 0; dk < 3; ++dk) {
            float ix = Px + Qx[dk];
            float iy = Py + Qy[dk];
            bool valid = (ix >= 0.f) & (ix <= 199.f) & (iy >= 0.f) & (iy <= 199.f);
            float wx = fmaxf(0.f, 1.f - fabsf(ix - i1f));
            float wy = fmaxf(0.f, 1.f - fabsf(iy - i2f));
            float wxm = valid ? wx : 0.f;
            w = fmaf(wxm, wy, w);
        }

        // all-gather the 4 dj-weights within the pixel-group (dj ascending)
        float w0 = __shfl(w, lb + 0);
        float w1 = __shfl(w, lb + 1);
        float w2 = __shfl(w, lb + 2);
        float w3 = __shfl(w, lb + 3);

        acc[0] = fmaf(w0, Z0.x, acc[0]); acc[1] = fmaf(w0, Z0.y, acc[1]);
        acc[2] = fmaf(w0, Z0.z, acc[2]); acc[3] = fmaf(w0, Z0.w, acc[3]);
        acc[0] = fmaf(w1, Z1.x, acc[0]); acc[1] = fmaf(w1, Z1.y, acc[1]);
        acc[2] = fmaf(w1, Z1.z, acc[2]); acc[3] = fmaf(w1, Z1.w, acc[3]);
        acc[0] = fmaf(w2, Z2.x, acc[0]); acc[1] = fmaf(w2, Z2.y, acc[1]);
        acc[2] = fmaf(w2, Z2.z, acc[2]); acc[3] = fmaf(w2, Z2.w, acc[3]);
        acc[0] = fmaf(w3, Z3.x, acc[0]); acc[1] = fmaf(w3, Z3.y, acc[1]);
        acc[2] = fmaf(w3, Z3.z, acc[2]); acc[3] = fmaf(w3, Z3.w, acc[3]);
    }

    float* pp = (pc == 0) ? q0 : (pc == 1) ? q1 : (pc == 2) ? q2 : (pc == 3) ? q3 : q4;
#pragma unroll
    for (int i = 0; i < 4; ++i)
        pp[(q * 4 + i) * NPIX + pix] = acc[i] * 2.0f;   // * STEP, plain store
}

extern "C" void kernel_launch(void* const* d_in, const int* in_sizes, int n_in,
                              void* d_out, int out_size, void* d_ws, size_t ws_size,
                              hipStream_t stream) {
    const float* x      = (const float*)d_in[0];
    const float* data   = (const float*)d_in[1];
    const float* contam = (const float*)d_in[2];
    const float* mult   = (const float*)d_in[3];
    const float* sens   = (const float*)d_in[4];
    float* out = (float*)d_out;

    float* W    = (float*)d_ws;
    float* s    = W;                        // 640000
    float* tmp  = W + NVOX;                 // 640000
    float* bp2  = W + 2 * NVOX;             // 640000
    float* zt   = W + 3 * NVOX;             // 677920
    float* P16  = W + 3 * NVOX + NSINO;     // 698880
    float* PT16 = P16 + S16;                // 698880
    float* cosb = PT16 + S16;
    float* sinb = cosb + NUM_PHI;
    float* rvb  = sinb + NUM_PHI;
    float* gwb  = rvb + NUM_RAD;

    hipLaunchKernelGGL(init_consts, dim3(1), dim3(256), 0, stream, cosb, sinb, rvb, gwb);

    // gauss3 forward: x -> s (axis0), s -> tmp (axis1), tmp -> {P16, PT16} (axis2, 16-interleave)
    int nb = (NVOX + 255) / 256;
    hipLaunchKernelGGL(smooth_fwd, dim3(nb), dim3(256), 0, stream, x,   s,   gwb, N0, NPIX);
    hipLaunchKernelGGL(smooth_fwd, dim3(nb), dim3(256), 0, stream, s,   tmp, gwb, N1, N2);
    int nb2 = (2 * NPIX + 255) / 256;
    hipLaunchKernelGGL(smooth_fwd2_16, dim3(nb2), dim3(256), 0, stream, tmp, P16, PT16, gwb);

    // forward project + ratio (writes zt): 760 blocks, round-3 XCD swizzle
    hipLaunchKernelGGL(project_ratio, dim3(NUM_PHI * 4), dim3(256, 2), 0, stream,
                       P16, PT16, data, contam, mult, cosb, sinb, rvb, zt);

    // backproject: 5 private partial volumes in dead buffers (s, tmp, bp2, P16, PT16)
    hipLaunchKernelGGL(backproject, dim3(NPIX / 64, BP_NCH), dim3(256), 0, stream,
                       zt, cosb, sinb, rvb, s, tmp, bp2, P16, PT16);

    // gauss3 adjoint with fused 5-partial fold:
    //   {q0..q4} -> zt (axis2^T + sum5), zt -> s (axis1^T), s -> out (axis0^T fused final)
    hipLaunchKernelGGL(smooth_adj2_sum5, dim3(nb), dim3(256), 0, stream,
                       s, tmp, bp2, P16, PT16, gwb, zt);
    hipLaunchKernelGGL(smooth_adj, dim3(nb), dim3(256), 0, stream, zt, s, gwb, N1, N2);
    hipLaunchKernelGGL(smooth_adj0_final, dim3(nb), dim3(256), 0, stream, s, x, sens, gwb, out);
}